// Round 7
// baseline (1444.333 us; speedup 1.0000x reference)
//
#include <hip/hip_runtime.h>
#include <hip/hip_bf16.h>

constexpr int B    = 16;
constexpr int N    = 4096;
constexpr int CIN  = 64;
constexpr int COUT = 128;
constexpr int M    = 1024;
constexpr int K    = 32;

constexpr int K1  = 96;   // layer-1 MFMA K: 64 x + 3 rel + 29 zero pad
constexpr int LD1 = 104;  // sA1 row stride (pad +8)
constexpr int LD2 = 136;  // sA2 row stride (pad +8)

constexpr int FPS_T = 256;        // threads (4 waves)
constexpr int PPT   = N / FPS_T;  // 16 points per thread

typedef __attribute__((ext_vector_type(8))) short short8;
typedef __attribute__((ext_vector_type(4))) float f32x4;

// RNE float->bf16 (finite values)
static __device__ __forceinline__ unsigned short f2bf(float f) {
  unsigned u = __float_as_uint(f);
  unsigned r = (u + 0x7FFFu + ((u >> 16) & 1u)) >> 16;
  return (unsigned short)r;
}

// fast mish: v * tanh(softplus(v)) == v * s/(s+2), s = u^2+2u, u = e^v
static __device__ __forceinline__ float fast_mish(float v) {
  float u = __expf(v);
  float s = u * (u + 2.0f);
  float t = s / (s + 2.0f);
  return (v > 60.f) ? v : v * t;
}

// ---------------------------------------------------------------------------
// Wave-wide u32 max via DPP (row_shr 1/2/4/8, row_bcast 15/31, readlane 63).
// ---------------------------------------------------------------------------
template <int CTRL, int RM>
static __device__ __forceinline__ unsigned dpp_umax_step(unsigned x) {
  int o = __builtin_amdgcn_update_dpp((int)x, (int)x, CTRL, RM, 0xF, false);
  unsigned u = (unsigned)o;
  return x > u ? x : u;
}
static __device__ __forceinline__ unsigned wave_umax(unsigned x) {
  x = dpp_umax_step<0x111, 0xF>(x);  // row_shr:1
  x = dpp_umax_step<0x112, 0xF>(x);  // row_shr:2
  x = dpp_umax_step<0x114, 0xF>(x);  // row_shr:4
  x = dpp_umax_step<0x118, 0xF>(x);  // row_shr:8
  x = dpp_umax_step<0x142, 0xA>(x);  // row_bcast:15 -> rows 1,3
  x = dpp_umax_step<0x143, 0xC>(x);  // row_bcast:31 -> rows 2,3
  return (unsigned)__builtin_amdgcn_readlane((int)x, 63);
}

// ---------------------------------------------------------------------------
// FPS: one block per cloud, 256 threads (4 waves), 16 pts/lane in registers.
// Per iter: dist update -> DPP argmax (value, then inv-index tie-break) ->
// wave winner lane writes {key,x,y,z} record -> ONE barrier -> all threads
// read 4 records + z4 (5x b128 broadcast) -> in-register tournament gives
// winner index AND coords (no dependent sp[n] read). Writes idx + q + pos4.
// ---------------------------------------------------------------------------
__global__ __launch_bounds__(FPS_T) void fps5_kernel(const float* __restrict__ pos,
                                                     int* __restrict__ idx_out,
                                                     float* __restrict__ pout,
                                                     float* __restrict__ pos4) {
#pragma clang fp contract(off)
  const int b   = blockIdx.x;
  const int tid = threadIdx.x;
  __shared__ float sp[N][4];
  __shared__ float sKA[2][4][4];  // {asf(inv_n), asf(dist_bits), x, y}
  __shared__ float sKZ[2][4];     // z
  const float* p = pos + (size_t)b * (N * 3);
  for (int i = tid; i < N; i += FPS_T) {
    sp[i][0] = p[3 * i + 0];
    sp[i][1] = p[3 * i + 1];
    sp[i][2] = p[3 * i + 2];
    sp[i][3] = 0.f;
  }
  __syncthreads();

  // dump packed pos4 for knn (coalesced b128 stores, fire-and-forget)
  float* p4 = pos4 + (size_t)b * N * 4;
  for (int i = tid; i < N; i += FPS_T) {
    *(f32x4*)(p4 + 4 * i) = *(const f32x4*)(&sp[i][0]);
  }

  float px[PPT], py[PPT], pz[PPT], mind[PPT];
#pragma unroll
  for (int i = 0; i < PPT; i++) {
    const int n = tid + i * FPS_T;
    px[i] = sp[n][0];
    py[i] = sp[n][1];
    pz[i] = sp[n][2];
    mind[i] = __builtin_inff();
  }
  float qx = sp[0][0], qy = sp[0][1], qz = sp[0][2];
  if (tid == 0) {
    idx_out[b * M + 0] = 0;
    pout[(size_t)(b * M + 0) * 3 + 0] = qx;
    pout[(size_t)(b * M + 0) * 3 + 1] = qy;
    pout[(size_t)(b * M + 0) * 3 + 2] = qz;
  }

  const int wv = tid >> 6;
  for (int t = 1; t < M; t++) {
    float bv = -1.f;
    unsigned bn = 0;
#pragma unroll
    for (int i = 0; i < PPT; i++) {
      float dx = px[i] - qx;
      float dy = py[i] - qy;
      float dz = pz[i] - qz;
      float d = (dx * dx + dy * dy) + dz * dz;  // numpy order, no fma
      float mi = fminf(mind[i], d);
      mind[i] = mi;
      bool c = mi > bv;  // strict: ascending n keeps smallest index on ties
      bv = c ? mi : bv;
      bn = c ? (unsigned)(tid + i * FPS_T) : bn;
    }
    const unsigned vb = __float_as_uint(bv);  // nonneg floats: monotone bits
    const unsigned wb = wave_umax(vb);        // wave max value
    unsigned tk = (vb == wb) ? ~bn : 0u;
    tk = wave_umax(tk);                       // ties -> smallest n
    const unsigned win_n = ~tk;
    const int par = t & 1;
    if (bn == win_n) {  // unique lane: owns the winner point
      float wx = 0.f, wy = 0.f, wz = 0.f;
#pragma unroll
      for (int i = 0; i < PPT; i++) {
        if (bn == (unsigned)(tid + i * FPS_T)) { wx = px[i]; wy = py[i]; wz = pz[i]; }
      }
      f32x4 rec;
      rec[0] = __uint_as_float(tk);
      rec[1] = __uint_as_float(wb);
      rec[2] = wx;
      rec[3] = wy;
      *(f32x4*)(&sKA[par][wv][0]) = rec;
      sKZ[par][wv] = wz;
    }
    __syncthreads();
    const f32x4 r0 = *(const f32x4*)(&sKA[par][0][0]);
    const f32x4 r1 = *(const f32x4*)(&sKA[par][1][0]);
    const f32x4 r2 = *(const f32x4*)(&sKA[par][2][0]);
    const f32x4 z4 = *(const f32x4*)(&sKZ[par][0]);
    const f32x4 r3 = *(const f32x4*)(&sKA[par][3][0]);
    const unsigned long long k0 = ((unsigned long long)__float_as_uint(r0[1]) << 32) | __float_as_uint(r0[0]);
    const unsigned long long k1 = ((unsigned long long)__float_as_uint(r1[1]) << 32) | __float_as_uint(r1[0]);
    const unsigned long long k2 = ((unsigned long long)__float_as_uint(r2[1]) << 32) | __float_as_uint(r2[0]);
    const unsigned long long k3 = ((unsigned long long)__float_as_uint(r3[1]) << 32) | __float_as_uint(r3[0]);
    const bool cA = k1 > k0;
    const f32x4 rA = cA ? r1 : r0;
    const float zA = cA ? z4[1] : z4[0];
    const unsigned long long kA = cA ? k1 : k0;
    const bool cB = k3 > k2;
    const f32x4 rB = cB ? r3 : r2;
    const float zB = cB ? z4[3] : z4[2];
    const unsigned long long kB = cB ? k3 : k2;
    const bool cC = kB > kA;
    const f32x4 rW = cC ? rB : rA;
    qz = cC ? zB : zA;
    qx = rW[2];
    qy = rW[3];
    const unsigned n = ~__float_as_uint(rW[0]);
    if (tid == 0) {
      idx_out[b * M + t] = (int)n;
      pout[(size_t)(b * M + t) * 3 + 0] = qx;
      pout[(size_t)(b * M + t) * 3 + 1] = qy;
      pout[(size_t)(b * M + t) * 3 + 2] = qz;
    }
  }
}

// ---------------------------------------------------------------------------
// KNN: one wave per centroid, 4 same-cloud waves/block. d[64] via packed
// pos4 b128 loads; 8 cached group-minima; per round DPP argmin + winner-group
// rescan (scalar-uniform branch).
// ---------------------------------------------------------------------------
__global__ __launch_bounds__(256) void knn4_kernel(const float* __restrict__ pos4,
                                                   const int* __restrict__ idx,
                                                   int* __restrict__ nbr) {
#pragma clang fp contract(off)
  const int wv   = threadIdx.x >> 6;
  const int lane = threadIdx.x & 63;
  const int cent = blockIdx.x * 4 + wv;
  const int b = cent >> 10;
  const float* p4 = pos4 + (size_t)b * N * 4;
  const int sel = idx[cent];
  const f32x4 q = *(const f32x4*)(p4 + 4 * sel);

  float d[64];
#pragma unroll
  for (int j = 0; j < 64; j++) {
    const f32x4 v = *(const f32x4*)(p4 + 4 * (j * 64 + lane));
    float dx = q[0] - v[0];
    float dy = q[1] - v[1];
    float dz = q[2] - v[2];
    d[j] = (dx * dx + dy * dy) + dz * dz;  // numpy order, no fma
  }
  float gv[8];
  int gj[8];
#pragma unroll
  for (int g = 0; g < 8; g++) {
    gv[g] = __builtin_inff();
    gj[g] = 8 * g;
#pragma unroll
    for (int e = 0; e < 8; e++) {
      const int j = 8 * g + e;
      bool c = d[j] < gv[g];  // strict: ascending j keeps smallest on ties
      gv[g] = c ? d[j] : gv[g];
      gj[g] = c ? j : gj[g];
    }
  }

  int* out = nbr + (size_t)cent * K;
  for (int r = 0; r < K; r++) {
    float bv = __builtin_inff();
    int bj = 0;
#pragma unroll
    for (int g = 0; g < 8; g++) {
      bool c = gv[g] < bv;
      bv = c ? gv[g] : bv;
      bj = c ? gj[g] : bj;
    }
    const unsigned bn = (unsigned)(bj * 64 + lane);
    const unsigned nb = ~__float_as_uint(bv);  // ~bits: umax -> min distance
    const unsigned wnb = wave_umax(nb);
    unsigned tk = (nb == wnb) ? (0xFFFFFFFFu - bn) : 0u;
    tk = wave_umax(tk);                        // ties -> smallest global n
    const unsigned wn = 0xFFFFFFFFu - tk;      // uniform across wave
    if (lane == 0) out[r] = (int)wn;

    const int wj = (int)(wn >> 6);
    const int wl = (int)(wn & 63);
    const int wg = wj >> 3;
#pragma unroll
    for (int g = 0; g < 8; g++) {
      if (g == wg) {  // scalar-uniform: only winner's group pays
#pragma unroll
        for (int e = 0; e < 8; e++) {
          if (8 * g + e == wj) {
            if (lane == wl) d[8 * g + e] = __builtin_inff();
          }
        }
        float nv = __builtin_inff();
        int nj = 8 * g;
#pragma unroll
        for (int e = 0; e < 8; e++) {
          const int j = 8 * g + e;
          bool c = d[j] < nv;
          nv = c ? d[j] : nv;
          nj = c ? j : nj;
        }
        gv[g] = nv;
        gj[g] = nj;
      }
    }
  }
}

// ---------------------------------------------------------------------------
// Weight prep: W1t[n][k] = bf16(W1[k][n]) for k<67 else 0   (n<128, k<96)
//              W2t[n][k] = bf16(W2[k][n])                   (n<128, k<128)
// ---------------------------------------------------------------------------
__global__ __launch_bounds__(256) void prep_weights(const float* __restrict__ W1,
                                                    const float* __restrict__ W2,
                                                    unsigned short* __restrict__ W1t,
                                                    unsigned short* __restrict__ W2t) {
  const int n = blockIdx.x;    // 128
  const int t = threadIdx.x;   // 256
  if (t < K1) {
    W1t[n * K1 + t] = (t < 67) ? f2bf(W1[t * 128 + n]) : (unsigned short)0;
  } else if (t < K1 + 128) {
    int k = t - K1;
    W2t[n * 128 + k] = f2bf(W2[k * 128 + n]);
  }
}

// ---------------------------------------------------------------------------
// Fused MLP (MFMA): 8 centroids/block, 256 threads (4 waves).
// ---------------------------------------------------------------------------
constexpr int FB_CENT = 8;
__global__ __launch_bounds__(256) void mlp_mfma_kernel(
    const float* __restrict__ x, const float* __restrict__ pos,
    const unsigned short* __restrict__ W1t, const unsigned short* __restrict__ W2t,
    const float* __restrict__ b1, const float* __restrict__ b2,
    const float* __restrict__ Wlin, const float* __restrict__ blin,
    const int* __restrict__ idx, const int* __restrict__ nbr,
    float* __restrict__ xout) {
  __shared__ unsigned short sA1[32][LD1];
  __shared__ unsigned short sA2[32][LD2];
  __shared__ float sB1[128];
  __shared__ float sAgg[2][128];
  __shared__ float sXsel[64];
  __shared__ int sNbr[K];
  const int tid  = threadIdx.x;
  const int wv   = tid >> 6;
  const int lane = tid & 63;
  const int mt   = wv & 1;
  const int ntb  = (wv >> 1) * 4;
  const int lrow = lane & 15;
  const int lk   = (lane >> 4) * 8;

  if (tid < 128) sB1[tid] = b1[tid];

  const int cent0 = blockIdx.x * FB_CENT;
  for (int c = 0; c < FB_CENT; c++) {
    const int cent = cent0 + c;
    const int b = cent >> 10;
    __syncthreads();
    const int sel = idx[cent];
    const float* pb = pos + (size_t)b * (N * 3);
    const float qx = pb[sel * 3 + 0], qy = pb[sel * 3 + 1], qz = pb[sel * 3 + 2];
    if (tid < K) sNbr[tid] = nbr[(size_t)cent * K + tid];
    if (tid < 64) sXsel[tid] = x[((size_t)b * N + sel) * CIN + tid];
    __syncthreads();

    {
      const int row = tid >> 3;
      const int cg = tid & 7;
      const int n = sNbr[row];
      const float* xr = x + ((size_t)b * N + n) * CIN + cg * 8;
      f32x4 v0 = *(const f32x4*)(xr);
      f32x4 v1 = *(const f32x4*)(xr + 4);
      short8 hv;
#pragma unroll
      for (int e = 0; e < 4; e++) {
        hv[e]     = (short)f2bf(v0[e]);
        hv[e + 4] = (short)f2bf(v1[e]);
      }
      *(short8*)(&sA1[row][cg * 8]) = hv;
      if (cg == 0) {
        float rx = pb[n * 3 + 0] - qx, ry = pb[n * 3 + 1] - qy, rz = pb[n * 3 + 2] - qz;
        short8 r0 = {};
        r0[0] = (short)f2bf(rx);
        r0[1] = (short)f2bf(ry);
        r0[2] = (short)f2bf(rz);
        *(short8*)(&sA1[row][64]) = r0;
        short8 z = {};
        *(short8*)(&sA1[row][72]) = z;
        *(short8*)(&sA1[row][80]) = z;
        *(short8*)(&sA1[row][88]) = z;
      }
    }
    __syncthreads();

    f32x4 acc1[4] = {};
#pragma unroll
    for (int kc = 0; kc < 3; kc++) {
      short8 af = *(const short8*)(&sA1[mt * 16 + lrow][kc * 32 + lk]);
#pragma unroll
      for (int i = 0; i < 4; i++) {
        short8 bfr = *(const short8*)(W1t + ((size_t)((ntb + i) * 16 + lrow)) * K1 + kc * 32 + lk);
        acc1[i] = __builtin_amdgcn_mfma_f32_16x16x32_bf16(af, bfr, acc1[i], 0, 0, 0);
      }
    }
#pragma unroll
    for (int i = 0; i < 4; i++) {
      const int colI = (ntb + i) * 16 + lrow;
      const float bb = sB1[colI];
#pragma unroll
      for (int reg = 0; reg < 4; reg++) {
        const int row = mt * 16 + (lane >> 4) * 4 + reg;
        sA2[row][colI] = f2bf(fast_mish(acc1[i][reg] + bb));
      }
    }
    __syncthreads();

    f32x4 acc2[4] = {};
#pragma unroll
    for (int kc = 0; kc < 4; kc++) {
      short8 af = *(const short8*)(&sA2[mt * 16 + lrow][kc * 32 + lk]);
#pragma unroll
      for (int i = 0; i < 4; i++) {
        short8 bfr = *(const short8*)(W2t + ((size_t)((ntb + i) * 16 + lrow)) * 128 + kc * 32 + lk);
        acc2[i] = __builtin_amdgcn_mfma_f32_16x16x32_bf16(af, bfr, acc2[i], 0, 0, 0);
      }
    }
#pragma unroll
    for (int i = 0; i < 4; i++) {
      float pm = fmaxf(fmaxf(acc2[i][0], acc2[i][1]), fmaxf(acc2[i][2], acc2[i][3]));
      pm = fmaxf(pm, __shfl_xor(pm, 16, 64));
      pm = fmaxf(pm, __shfl_xor(pm, 32, 64));
      if (lane < 16) sAgg[mt][(ntb + i) * 16 + lane] = pm;
    }
    __syncthreads();

    if (tid < 128) {
      const int j = tid;
      float v = fmaxf(sAgg[0][j], sAgg[1][j]) + b2[j];
      float lin = blin[j];
      for (int kg = 0; kg < 16; kg++) {
        f32x4 xv = *(const f32x4*)(&sXsel[kg * 4]);
        lin += xv[0] * Wlin[(kg * 4 + 0) * 128 + j] + xv[1] * Wlin[(kg * 4 + 1) * 128 + j] +
               xv[2] * Wlin[(kg * 4 + 2) * 128 + j] + xv[3] * Wlin[(kg * 4 + 3) * 128 + j];
      }
      xout[(size_t)cent * 128 + j] = v + lin;
    }
  }
}

// ---------------------------------------------------------------------------
extern "C" void kernel_launch(void* const* d_in, const int* in_sizes, int n_in,
                              void* d_out, int out_size, void* d_ws, size_t ws_size,
                              hipStream_t stream) {
  const float* x    = (const float*)d_in[0];
  const float* pos  = (const float*)d_in[1];
  const float* W1   = (const float*)d_in[2];
  const float* b1   = (const float*)d_in[3];
  const float* W2   = (const float*)d_in[4];
  const float* b2   = (const float*)d_in[5];
  const float* Wlin = (const float*)d_in[6];
  const float* blin = (const float*)d_in[7];

  float* out  = (float*)d_out;                 // float32 outputs
  float* xout = out;                           // [B*M*COUT]
  float* pout = out + (size_t)B * M * COUT;    // [B*M*3]

  char* ws = (char*)d_ws;
  int* idx            = (int*)ws;                                         // 64 KB
  int* nbr            = (int*)(ws + 65536);                               // 2 MB
  unsigned short* W1t = (unsigned short*)(ws + 65536 + 2097152);          // 24 KB
  unsigned short* W2t = (unsigned short*)(ws + 65536 + 2097152 + 24576);  // 32 KB
  float* pos4         = (float*)(ws + 65536 + 2097152 + 24576 + 32768);   // 1 MB

  prep_weights<<<dim3(128), dim3(256), 0, stream>>>(W1, W2, W1t, W2t);
  fps5_kernel<<<dim3(B), dim3(FPS_T), 0, stream>>>(pos, idx, pout, pos4);
  knn4_kernel<<<dim3(B * M / 4), dim3(256), 0, stream>>>(pos4, idx, nbr);
  mlp_mfma_kernel<<<dim3(B * M / FB_CENT), dim3(256), 0, stream>>>(
      x, pos, W1t, W2t, b1, b2, Wlin, blin, idx, nbr, xout);
}

// Round 8
// 1195.239 us; speedup vs baseline: 1.2084x; 1.2084x over previous
//
#include <hip/hip_runtime.h>
#include <hip/hip_bf16.h>

constexpr int B    = 16;
constexpr int N    = 4096;
constexpr int CIN  = 64;
constexpr int COUT = 128;
constexpr int M    = 1024;
constexpr int K    = 32;

constexpr int K1  = 96;   // layer-1 MFMA K: 64 x + 3 rel + 29 zero pad
constexpr int LDH = 136;  // sA2 row stride (pad +8)

typedef __attribute__((ext_vector_type(8))) short short8;
typedef __attribute__((ext_vector_type(4))) float f32x4;

// RNE float->bf16 (finite values)
static __device__ __forceinline__ unsigned short f2bf(float f) {
  unsigned u = __float_as_uint(f);
  unsigned r = (u + 0x7FFFu + ((u >> 16) & 1u)) >> 16;
  return (unsigned short)r;
}

// fast mish: v * tanh(softplus(v)) == v * s/(s+2), s = u^2+2u, u = e^v
static __device__ __forceinline__ float fast_mish(float v) {
  float u = __expf(v);
  float s = u * (u + 2.0f);
  float t = s / (s + 2.0f);
  return (v > 60.f) ? v : v * t;
}

// ---------------------------------------------------------------------------
// Wave-wide u32 max via DPP (row_shr 1/2/4/8, row_bcast 15/31, readlane 63).
// ---------------------------------------------------------------------------
template <int CTRL, int RM>
static __device__ __forceinline__ unsigned dpp_umax_step(unsigned x) {
  int o = __builtin_amdgcn_update_dpp((int)x, (int)x, CTRL, RM, 0xF, false);
  unsigned u = (unsigned)o;
  return x > u ? x : u;
}
static __device__ __forceinline__ unsigned wave_umax(unsigned x) {
  x = dpp_umax_step<0x111, 0xF>(x);  // row_shr:1
  x = dpp_umax_step<0x112, 0xF>(x);  // row_shr:2
  x = dpp_umax_step<0x114, 0xF>(x);  // row_shr:4
  x = dpp_umax_step<0x118, 0xF>(x);  // row_shr:8
  x = dpp_umax_step<0x142, 0xA>(x);  // row_bcast:15 -> rows 1,3
  x = dpp_umax_step<0x143, 0xC>(x);  // row_bcast:31 -> rows 2,3
  return (unsigned)__builtin_amdgcn_readlane((int)x, 63);
}

// ---------------------------------------------------------------------------
// FPS: one block/cloud, 512 threads (8 waves -> 2/SIMD latency hiding),
// 8 pts/lane in registers, NO point LDS. Per iter: dist update -> DPP argmax
// -> winner lane posts record {inv_n, dist_bits, x, y} + z -> ONE barrier ->
// depth-3 u64 tournament over 8 records gives next index AND coords in regs.
// Writes idx + q(f32) + packed pos4 for knn.
// ---------------------------------------------------------------------------
__global__ __launch_bounds__(512) void fps6_kernel(const float* __restrict__ pos,
                                                   int* __restrict__ idx_out,
                                                   float* __restrict__ pout,
                                                   float* __restrict__ pos4) {
#pragma clang fp contract(off)
  const int b   = blockIdx.x;
  const int tid = threadIdx.x;
  __shared__ float sKA[2][8][4];  // {asf(inv_n), asf(dist_bits), x, y}
  __shared__ float sKZ[2][8];     // z
  const float* p = pos + (size_t)b * (N * 3);
  float* p4 = pos4 + (size_t)b * N * 4;

  constexpr int PPT = N / 512;  // 8
  float px[PPT], py[PPT], pz[PPT], mind[PPT];
#pragma unroll
  for (int i = 0; i < PPT; i++) {
    const int n = tid + i * 512;
    px[i] = p[3 * n + 0];
    py[i] = p[3 * n + 1];
    pz[i] = p[3 * n + 2];
    mind[i] = __builtin_inff();
    f32x4 v;
    v[0] = px[i]; v[1] = py[i]; v[2] = pz[i]; v[3] = 0.f;
    *(f32x4*)(p4 + 4 * n) = v;  // packed dump for knn
  }
  float qx = p[0], qy = p[1], qz = p[2];
  if (tid == 0) {
    idx_out[b * M + 0] = 0;
    pout[(size_t)(b * M + 0) * 3 + 0] = qx;
    pout[(size_t)(b * M + 0) * 3 + 1] = qy;
    pout[(size_t)(b * M + 0) * 3 + 2] = qz;
  }

  const int wv = tid >> 6;
  for (int t = 1; t < M; t++) {
    float bv = -1.f;
    unsigned bn = 0;
#pragma unroll
    for (int i = 0; i < PPT; i++) {
      float dx = px[i] - qx;
      float dy = py[i] - qy;
      float dz = pz[i] - qz;
      float d = (dx * dx + dy * dy) + dz * dz;  // numpy order, no fma
      float mi = fminf(mind[i], d);
      mind[i] = mi;
      bool c = mi > bv;  // strict: ascending n keeps smallest index on ties
      bv = c ? mi : bv;
      bn = c ? (unsigned)(tid + i * 512) : bn;
    }
    const unsigned vb = __float_as_uint(bv);  // nonneg floats: monotone bits
    const unsigned wb = wave_umax(vb);        // wave max value
    unsigned tk = (vb == wb) ? ~bn : 0u;
    tk = wave_umax(tk);                       // ties -> smallest n
    const int par = t & 1;
    if (bn == ~tk) {  // unique winner lane of this wave
      float wx = 0.f, wy = 0.f, wz = 0.f;
#pragma unroll
      for (int i = 0; i < PPT; i++) {
        if (bn == (unsigned)(tid + i * 512)) { wx = px[i]; wy = py[i]; wz = pz[i]; }
      }
      f32x4 rec;
      rec[0] = __uint_as_float(tk);
      rec[1] = __uint_as_float(wb);
      rec[2] = wx;
      rec[3] = wy;
      *(f32x4*)(&sKA[par][wv][0]) = rec;
      sKZ[par][wv] = wz;
    }
    __syncthreads();
    // depth-3 tournament over 8 records (all threads, broadcast reads)
    f32x4 r0 = *(const f32x4*)(&sKA[par][0][0]);
    f32x4 r1 = *(const f32x4*)(&sKA[par][1][0]);
    f32x4 r2 = *(const f32x4*)(&sKA[par][2][0]);
    f32x4 r3 = *(const f32x4*)(&sKA[par][3][0]);
    f32x4 r4 = *(const f32x4*)(&sKA[par][4][0]);
    f32x4 r5 = *(const f32x4*)(&sKA[par][5][0]);
    f32x4 r6 = *(const f32x4*)(&sKA[par][6][0]);
    f32x4 r7 = *(const f32x4*)(&sKA[par][7][0]);
    f32x4 zlo = *(const f32x4*)(&sKZ[par][0]);
    f32x4 zhi = *(const f32x4*)(&sKZ[par][4]);
#define KEY(r) ((unsigned long long)__float_as_uint(r[1]) << 32 | __float_as_uint(r[0]))
    unsigned long long k0 = KEY(r0), k1 = KEY(r1), k2 = KEY(r2), k3 = KEY(r3);
    unsigned long long k4 = KEY(r4), k5 = KEY(r5), k6 = KEY(r6), k7 = KEY(r7);
#undef KEY
    bool c01 = k1 > k0; f32x4 rA = c01 ? r1 : r0; float zA = c01 ? zlo[1] : zlo[0]; unsigned long long kA = c01 ? k1 : k0;
    bool c23 = k3 > k2; f32x4 rB = c23 ? r3 : r2; float zB = c23 ? zlo[3] : zlo[2]; unsigned long long kB = c23 ? k3 : k2;
    bool c45 = k5 > k4; f32x4 rC = c45 ? r5 : r4; float zC = c45 ? zhi[1] : zhi[0]; unsigned long long kC = c45 ? k5 : k4;
    bool c67 = k7 > k6; f32x4 rD = c67 ? r7 : r6; float zD = c67 ? zhi[3] : zhi[2]; unsigned long long kD = c67 ? k7 : k6;
    bool cAB = kB > kA; f32x4 rE = cAB ? rB : rA; float zE = cAB ? zB : zA; unsigned long long kE = cAB ? kB : kA;
    bool cCD = kD > kC; f32x4 rF = cCD ? rD : rC; float zF = cCD ? zD : zC; unsigned long long kF = cCD ? kD : kC;
    bool cEF = kF > kE; f32x4 rW = cEF ? rF : rE;
    qz = cEF ? zF : zE;
    qx = rW[2];
    qy = rW[3];
    const unsigned n = ~__float_as_uint(rW[0]);
    if (tid == 0) {
      idx_out[b * M + t] = (int)n;
      pout[(size_t)(b * M + t) * 3 + 0] = qx;
      pout[(size_t)(b * M + t) * 3 + 1] = qy;
      pout[(size_t)(b * M + t) * 3 + 2] = qz;
    }
  }
}

// ---------------------------------------------------------------------------
// KNN: one wave per centroid, 4 same-cloud waves/block, packed pos4 b128
// loads; 8 cached group-minima; per round DPP argmin + winner-group rescan.
// ---------------------------------------------------------------------------
__global__ __launch_bounds__(256) void knn4_kernel(const float* __restrict__ pos4,
                                                   const int* __restrict__ idx,
                                                   int* __restrict__ nbr) {
#pragma clang fp contract(off)
  const int wv   = threadIdx.x >> 6;
  const int lane = threadIdx.x & 63;
  const int cent = blockIdx.x * 4 + wv;
  const int b = cent >> 10;
  const float* p4 = pos4 + (size_t)b * N * 4;
  const int sel = idx[cent];
  const f32x4 q = *(const f32x4*)(p4 + 4 * sel);

  float d[64];
#pragma unroll
  for (int j = 0; j < 64; j++) {
    const f32x4 v = *(const f32x4*)(p4 + 4 * (j * 64 + lane));
    float dx = q[0] - v[0];
    float dy = q[1] - v[1];
    float dz = q[2] - v[2];
    d[j] = (dx * dx + dy * dy) + dz * dz;  // numpy order, no fma
  }
  float gv[8];
  int gj[8];
#pragma unroll
  for (int g = 0; g < 8; g++) {
    gv[g] = __builtin_inff();
    gj[g] = 8 * g;
#pragma unroll
    for (int e = 0; e < 8; e++) {
      const int j = 8 * g + e;
      bool c = d[j] < gv[g];
      gv[g] = c ? d[j] : gv[g];
      gj[g] = c ? j : gj[g];
    }
  }

  int* out = nbr + (size_t)cent * K;
  for (int r = 0; r < K; r++) {
    float bv = __builtin_inff();
    int bj = 0;
#pragma unroll
    for (int g = 0; g < 8; g++) {
      bool c = gv[g] < bv;
      bv = c ? gv[g] : bv;
      bj = c ? gj[g] : bj;
    }
    const unsigned bn = (unsigned)(bj * 64 + lane);
    const unsigned nb = ~__float_as_uint(bv);  // ~bits: umax -> min distance
    const unsigned wnb = wave_umax(nb);
    unsigned tk = (nb == wnb) ? (0xFFFFFFFFu - bn) : 0u;
    tk = wave_umax(tk);                        // ties -> smallest global n
    const unsigned wn = 0xFFFFFFFFu - tk;      // uniform across wave
    if (lane == 0) out[r] = (int)wn;

    const int wj = (int)(wn >> 6);
    const int wl = (int)(wn & 63);
    const int wg = wj >> 3;
#pragma unroll
    for (int g = 0; g < 8; g++) {
      if (g == wg) {
#pragma unroll
        for (int e = 0; e < 8; e++) {
          if (8 * g + e == wj) {
            if (lane == wl) d[8 * g + e] = __builtin_inff();
          }
        }
        float nv = __builtin_inff();
        int nj = 8 * g;
#pragma unroll
        for (int e = 0; e < 8; e++) {
          const int j = 8 * g + e;
          bool c = d[j] < nv;
          nv = c ? d[j] : nv;
          nj = c ? j : nj;
        }
        gv[g] = nv;
        gj[g] = nj;
      }
    }
  }
}

// ---------------------------------------------------------------------------
// Weight prep: W1t[n][k] = bf16(W1[k][n]) for k<67 else 0   (n<128, k<96)
//              W2t[n][k] = bf16(W2[k][n])                   (n<128, k<128)
// ---------------------------------------------------------------------------
__global__ __launch_bounds__(256) void prep_weights(const float* __restrict__ W1,
                                                    const float* __restrict__ W2,
                                                    unsigned short* __restrict__ W1t,
                                                    unsigned short* __restrict__ W2t) {
  const int n = blockIdx.x;    // 128
  const int t = threadIdx.x;   // 256
  if (t < K1) {
    W1t[n * K1 + t] = (t < 67) ? f2bf(W1[t * 128 + n]) : (unsigned short)0;
  } else if (t < K1 + 128) {
    int k = t - K1;
    W2t[n * 128 + k] = f2bf(W2[k * 128 + n]);
  }
}

// ---------------------------------------------------------------------------
// MLP v3: wave-per-centroid, ZERO barriers. 256 threads = 4 waves = 4 cents.
// A1 fragments built in registers from gathered x/pos (no LDS staging);
// only mish output crosses lanes via wave-private sA2 slice.
// L1: 8nt x 2mt x 3kc MFMA; L2: 8nt x 2mt x 4kc MFMA; epilogue in-wave.
// ---------------------------------------------------------------------------
__global__ __launch_bounds__(256) void mlp3_kernel(
    const float* __restrict__ x, const float* __restrict__ pos,
    const unsigned short* __restrict__ W1t, const unsigned short* __restrict__ W2t,
    const float* __restrict__ b1, const float* __restrict__ b2,
    const float* __restrict__ Wlin, const float* __restrict__ blin,
    const int* __restrict__ idx, const int* __restrict__ nbr,
    float* __restrict__ xout) {
  __shared__ unsigned short sA2[4][32][LDH];
  const int tid  = threadIdx.x;
  const int wv   = tid >> 6;
  const int lane = tid & 63;
  const int lrow = lane & 15;
  const int g    = lane >> 4;
  const int cent = blockIdx.x * 4 + wv;
  const int b    = cent >> 10;
  const int sel  = idx[cent];
  const float* pb = pos + (size_t)b * (N * 3);
  const float qx = pb[3 * sel + 0], qy = pb[3 * sel + 1], qz = pb[3 * sel + 2];
  unsigned short* A2 = &sA2[wv][0][0];

  // rows owned by this lane: r0 = lrow, r1 = 16 + lrow
  const int n0 = nbr[(size_t)cent * K + lrow];
  const int n1 = nbr[(size_t)cent * K + 16 + lrow];

  // ---- build A1 fragments in registers ----
  short8 a0[3], a1[3];  // [kc] for row0, row1
  {
    const float* xr0 = x + ((size_t)b * N + n0) * CIN;
    const float* xr1 = x + ((size_t)b * N + n1) * CIN;
#pragma unroll
    for (int kc = 0; kc < 2; kc++) {
      const int k0 = kc * 32 + g * 8;
      f32x4 u0 = *(const f32x4*)(xr0 + k0);
      f32x4 u1 = *(const f32x4*)(xr0 + k0 + 4);
      f32x4 v0 = *(const f32x4*)(xr1 + k0);
      f32x4 v1 = *(const f32x4*)(xr1 + k0 + 4);
      short8 ha, hb;
#pragma unroll
      for (int e = 0; e < 4; e++) {
        ha[e] = (short)f2bf(u0[e]);
        ha[e + 4] = (short)f2bf(u1[e]);
        hb[e] = (short)f2bf(v0[e]);
        hb[e + 4] = (short)f2bf(v1[e]);
      }
      a0[kc] = ha;
      a1[kc] = hb;
    }
    short8 z = {};
    a0[2] = z;
    a1[2] = z;
    if (g == 0) {  // k = 64..71: {rel.x, rel.y, rel.z, 0...}
      float r0x = pb[3 * n0 + 0] - qx, r0y = pb[3 * n0 + 1] - qy, r0z = pb[3 * n0 + 2] - qz;
      float r1x = pb[3 * n1 + 0] - qx, r1y = pb[3 * n1 + 1] - qy, r1z = pb[3 * n1 + 2] - qz;
      a0[2][0] = (short)f2bf(r0x); a0[2][1] = (short)f2bf(r0y); a0[2][2] = (short)f2bf(r0z);
      a1[2][0] = (short)f2bf(r1x); a1[2][1] = (short)f2bf(r1y); a1[2][2] = (short)f2bf(r1z);
    }
  }

  // ---- layer 1: C1[32,128] = A1 @ W1t^T, mish -> sA2 (wave-private) ----
#pragma unroll 2
  for (int nt = 0; nt < 8; nt++) {
    const unsigned short* w1r = W1t + (size_t)(nt * 16 + lrow) * K1 + g * 8;
    f32x4 c0 = {}, c1 = {};
#pragma unroll
    for (int kc = 0; kc < 3; kc++) {
      short8 bfr = *(const short8*)(w1r + kc * 32);
      c0 = __builtin_amdgcn_mfma_f32_16x16x32_bf16(a0[kc], bfr, c0, 0, 0, 0);
      c1 = __builtin_amdgcn_mfma_f32_16x16x32_bf16(a1[kc], bfr, c1, 0, 0, 0);
    }
    const int colI = nt * 16 + lrow;
    const float bb = b1[colI];
#pragma unroll
    for (int reg = 0; reg < 4; reg++) {
      const int row = g * 4 + reg;  // C layout (m89): col=lane&15, row=(lane>>4)*4+reg
      A2[row * LDH + colI] = f2bf(fast_mish(c0[reg] + bb));
      A2[(16 + row) * LDH + colI] = f2bf(fast_mish(c1[reg] + bb));
    }
  }

  // xsel slice for this lane's k-range (k = g*16 .. g*16+15)
  f32x4 xq[4];
  {
    const float* xs = x + ((size_t)b * N + sel) * CIN + g * 16;
#pragma unroll
    for (int v = 0; v < 4; v++) xq[v] = *(const f32x4*)(xs + 4 * v);
  }

  // ---- layer 2 + max over 32 rows + epilogue ----
#pragma unroll 2
  for (int nt = 0; nt < 8; nt++) {
    const unsigned short* w2r = W2t + (size_t)(nt * 16 + lrow) * 128 + g * 8;
    f32x4 c0 = {}, c1 = {};
#pragma unroll
    for (int kc = 0; kc < 4; kc++) {
      short8 af0 = *(const short8*)(A2 + lrow * LDH + kc * 32 + g * 8);
      short8 af1 = *(const short8*)(A2 + (16 + lrow) * LDH + kc * 32 + g * 8);
      short8 bfr = *(const short8*)(w2r + kc * 32);
      c0 = __builtin_amdgcn_mfma_f32_16x16x32_bf16(af0, bfr, c0, 0, 0, 0);
      c1 = __builtin_amdgcn_mfma_f32_16x16x32_bf16(af1, bfr, c1, 0, 0, 0);
    }
    float pm = fmaxf(fmaxf(fmaxf(c0[0], c0[1]), fmaxf(c0[2], c0[3])),
                     fmaxf(fmaxf(c1[0], c1[1]), fmaxf(c1[2], c1[3])));
    pm = fmaxf(pm, __shfl_xor(pm, 16, 64));
    pm = fmaxf(pm, __shfl_xor(pm, 32, 64));  // max over all 32 rows, col j
    const int j = nt * 16 + lrow;
    float s = 0.f;
#pragma unroll
    for (int e = 0; e < 16; e++) {
      s += xq[e >> 2][e & 3] * Wlin[(g * 16 + e) * 128 + j];
    }
    s += __shfl_xor(s, 16, 64);
    s += __shfl_xor(s, 32, 64);  // full 64-k dot
    if (g == 0) {
      xout[(size_t)cent * 128 + j] = pm + b2[j] + s + blin[j];
    }
  }
}

// ---------------------------------------------------------------------------
extern "C" void kernel_launch(void* const* d_in, const int* in_sizes, int n_in,
                              void* d_out, int out_size, void* d_ws, size_t ws_size,
                              hipStream_t stream) {
  const float* x    = (const float*)d_in[0];
  const float* pos  = (const float*)d_in[1];
  const float* W1   = (const float*)d_in[2];
  const float* b1   = (const float*)d_in[3];
  const float* W2   = (const float*)d_in[4];
  const float* b2   = (const float*)d_in[5];
  const float* Wlin = (const float*)d_in[6];
  const float* blin = (const float*)d_in[7];

  float* out  = (float*)d_out;                 // float32 outputs
  float* xout = out;                           // [B*M*COUT]
  float* pout = out + (size_t)B * M * COUT;    // [B*M*3]

  char* ws = (char*)d_ws;
  int* idx            = (int*)ws;                                         // 64 KB
  int* nbr            = (int*)(ws + 65536);                               // 2 MB
  unsigned short* W1t = (unsigned short*)(ws + 65536 + 2097152);          // 24 KB
  unsigned short* W2t = (unsigned short*)(ws + 65536 + 2097152 + 24576);  // 32 KB
  float* pos4         = (float*)(ws + 65536 + 2097152 + 24576 + 32768);   // 1 MB

  prep_weights<<<dim3(128), dim3(256), 0, stream>>>(W1, W2, W1t, W2t);
  fps6_kernel<<<dim3(B), dim3(512), 0, stream>>>(pos, idx, pout, pos4);
  knn4_kernel<<<dim3(B * M / 4), dim3(256), 0, stream>>>(pos4, idx, nbr);
  mlp3_kernel<<<dim3(B * M / 4), dim3(256), 0, stream>>>(
      x, pos, W1t, W2t, b1, b2, Wlin, blin, idx, nbr, xout);
}

// Round 9
// 941.912 us; speedup vs baseline: 1.5334x; 1.2689x over previous
//
#include <hip/hip_runtime.h>
#include <hip/hip_bf16.h>

constexpr int B    = 16;
constexpr int N    = 4096;
constexpr int CIN  = 64;
constexpr int COUT = 128;
constexpr int M    = 1024;
constexpr int K    = 32;

constexpr int K1  = 96;   // layer-1 MFMA K: 64 x + 3 rel + 29 zero pad
constexpr int LDH = 136;  // sA2 row stride (pad +8)

typedef __attribute__((ext_vector_type(8))) short short8;
typedef __attribute__((ext_vector_type(4))) float f32x4;
typedef __attribute__((ext_vector_type(2))) float f32x2;

// RNE float->bf16 (finite values)
static __device__ __forceinline__ unsigned short f2bf(float f) {
  unsigned u = __float_as_uint(f);
  unsigned r = (u + 0x7FFFu + ((u >> 16) & 1u)) >> 16;
  return (unsigned short)r;
}

// fast mish: v * tanh(softplus(v)) == v * s/(s+2), s = u^2+2u, u = e^v
static __device__ __forceinline__ float fast_mish(float v) {
  float u = __expf(v);
  float s = u * (u + 2.0f);
  float t = s / (s + 2.0f);
  return (v > 60.f) ? v : v * t;
}

// ---------------------------------------------------------------------------
// Wave-wide u32 max via DPP (row_shr 1/2/4/8, row_bcast 15/31, readlane 63).
// ---------------------------------------------------------------------------
template <int CTRL, int RM>
static __device__ __forceinline__ unsigned dpp_umax_step(unsigned x) {
  int o = __builtin_amdgcn_update_dpp((int)x, (int)x, CTRL, RM, 0xF, false);
  unsigned u = (unsigned)o;
  return x > u ? x : u;
}
static __device__ __forceinline__ unsigned wave_umax(unsigned x) {
  x = dpp_umax_step<0x111, 0xF>(x);  // row_shr:1
  x = dpp_umax_step<0x112, 0xF>(x);  // row_shr:2
  x = dpp_umax_step<0x114, 0xF>(x);  // row_shr:4
  x = dpp_umax_step<0x118, 0xF>(x);  // row_shr:8
  x = dpp_umax_step<0x142, 0xA>(x);  // row_bcast:15 -> rows 1,3
  x = dpp_umax_step<0x143, 0xC>(x);  // row_bcast:31 -> rows 2,3
  return (unsigned)__builtin_amdgcn_readlane((int)x, 63);
}

static __device__ __forceinline__ unsigned long long umax64(unsigned long long a,
                                                            unsigned long long b) {
  return a > b ? a : b;
}

// ---------------------------------------------------------------------------
// FPS: one block/cloud, 512 threads (8 waves = 2/SIMD), 8 pts/lane in regs as
// f32x2 pairs -> packed-FP32 distance math (v_pk_add/mul, IEEE-exact, half
// the ops). Reduce: DPP value-umax + inv-index tie umax -> lane0 posts u64
// key -> ONE barrier -> 8-way u64 tree -> dependent sp[n] b128 gives coords.
// Writes idx + q(f32) + packed pos4 for knn.
// ---------------------------------------------------------------------------
__global__ __launch_bounds__(512) void fps8_kernel(const float* __restrict__ pos,
                                                   int* __restrict__ idx_out,
                                                   float* __restrict__ pout,
                                                   float* __restrict__ pos4) {
#pragma clang fp contract(off)
  const int b   = blockIdx.x;
  const int tid = threadIdx.x;
  __shared__ float sp[N][4];
  __shared__ unsigned long long skey[2][8];
  const float* p = pos + (size_t)b * (N * 3);
  float* p4 = pos4 + (size_t)b * N * 4;

  // stage points: registers (paired) + sp (for winner-coord reads) + pos4 dump
  f32x2 px2[4], py2[4], pz2[4];
  float mind[8];
#pragma unroll
  for (int j = 0; j < 8; j++) {
    const int n = tid + j * 512;
    const float x = p[3 * n + 0];
    const float y = p[3 * n + 1];
    const float z = p[3 * n + 2];
    px2[j >> 1][j & 1] = x;
    py2[j >> 1][j & 1] = y;
    pz2[j >> 1][j & 1] = z;
    mind[j] = __builtin_inff();
    f32x4 v;
    v[0] = x; v[1] = y; v[2] = z; v[3] = 0.f;
    *(f32x4*)(&sp[n][0]) = v;
    *(f32x4*)(p4 + 4 * n) = v;
  }
  float qx = p[0], qy = p[1], qz = p[2];
  if (tid == 0) {
    idx_out[b * M + 0] = 0;
    pout[(size_t)(b * M + 0) * 3 + 0] = qx;
    pout[(size_t)(b * M + 0) * 3 + 1] = qy;
    pout[(size_t)(b * M + 0) * 3 + 2] = qz;
  }
  __syncthreads();

  const int wv = tid >> 6, lane = tid & 63;
  for (int t = 1; t < M; t++) {
    const f32x2 nqx = {-qx, -qx};
    const f32x2 nqy = {-qy, -qy};
    const f32x2 nqz = {-qz, -qz};
    float bv = -1.f;
    unsigned bn = 0;
#pragma unroll
    for (int k = 0; k < 4; k++) {
      f32x2 dx = px2[k] + nqx;                    // v_pk_add_f32 (exact sub)
      f32x2 dy = py2[k] + nqy;
      f32x2 dz = pz2[k] + nqz;
      f32x2 s = (dx * dx + dy * dy) + dz * dz;    // pk_mul x3, pk_add x2; numpy order
      const float mi0 = fminf(mind[2 * k + 0], s.x);
      mind[2 * k + 0] = mi0;
      bool c0 = mi0 > bv;   // strict >, ascending n: smallest index wins ties
      bv = c0 ? mi0 : bv;
      bn = c0 ? (unsigned)(tid + (2 * k + 0) * 512) : bn;
      const float mi1 = fminf(mind[2 * k + 1], s.y);
      mind[2 * k + 1] = mi1;
      bool c1 = mi1 > bv;
      bv = c1 ? mi1 : bv;
      bn = c1 ? (unsigned)(tid + (2 * k + 1) * 512) : bn;
    }
    const unsigned vb = __float_as_uint(bv);  // nonneg floats: monotone bits
    const unsigned wb = wave_umax(vb);        // wave max value
    unsigned tk = (vb == wb) ? ~bn : 0u;
    tk = wave_umax(tk);                       // ties -> smallest n
    const int par = t & 1;
    if (lane == 0) skey[par][wv] = ((unsigned long long)wb << 32) | tk;
    __syncthreads();
    const unsigned long long k0 = skey[par][0];
    const unsigned long long k1 = skey[par][1];
    const unsigned long long k2 = skey[par][2];
    const unsigned long long k3 = skey[par][3];
    const unsigned long long k4 = skey[par][4];
    const unsigned long long k5 = skey[par][5];
    const unsigned long long k6 = skey[par][6];
    const unsigned long long k7 = skey[par][7];
    const unsigned long long bb =
        umax64(umax64(umax64(k0, k1), umax64(k2, k3)),
               umax64(umax64(k4, k5), umax64(k6, k7)));
    const unsigned n = ~(unsigned)bb;
    const f32x4 qv = *(const f32x4*)(&sp[n][0]);  // one dependent b128 read
    qx = qv[0];
    qy = qv[1];
    qz = qv[2];
    if (tid == 0) {
      idx_out[b * M + t] = (int)n;
      pout[(size_t)(b * M + t) * 3 + 0] = qx;
      pout[(size_t)(b * M + t) * 3 + 1] = qy;
      pout[(size_t)(b * M + t) * 3 + 2] = qz;
    }
  }
}

// ---------------------------------------------------------------------------
// KNN: one wave per centroid, 4 same-cloud waves/block, packed pos4 b128
// loads + packed-FP32 distance init; 8 cached group-minima; per round DPP
// argmin + winner-group rescan (scalar-uniform branch).
// ---------------------------------------------------------------------------
__global__ __launch_bounds__(256) void knn5_kernel(const float* __restrict__ pos4,
                                                   const int* __restrict__ idx,
                                                   int* __restrict__ nbr) {
#pragma clang fp contract(off)
  const int wv   = threadIdx.x >> 6;
  const int lane = threadIdx.x & 63;
  const int cent = blockIdx.x * 4 + wv;
  const int b = cent >> 10;
  const float* p4 = pos4 + (size_t)b * N * 4;
  const int sel = idx[cent];
  const f32x4 q = *(const f32x4*)(p4 + 4 * sel);
  const f32x2 nqx = {-q[0], -q[0]};
  const f32x2 nqy = {-q[1], -q[1]};
  const f32x2 nqz = {-q[2], -q[2]};

  float d[64];
#pragma unroll
  for (int jj = 0; jj < 32; jj++) {
    const f32x4 v0 = *(const f32x4*)(p4 + 4 * ((2 * jj + 0) * 64 + lane));
    const f32x4 v1 = *(const f32x4*)(p4 + 4 * ((2 * jj + 1) * 64 + lane));
    f32x2 vx = {v0[0], v1[0]};
    f32x2 vy = {v0[1], v1[1]};
    f32x2 vz = {v0[2], v1[2]};
    f32x2 dx = vx + nqx;
    f32x2 dy = vy + nqy;
    f32x2 dz = vz + nqz;
    f32x2 s = (dx * dx + dy * dy) + dz * dz;  // numpy order, pk ops exact
    d[2 * jj + 0] = s.x;
    d[2 * jj + 1] = s.y;
  }
  float gv[8];
  int gj[8];
#pragma unroll
  for (int g = 0; g < 8; g++) {
    gv[g] = __builtin_inff();
    gj[g] = 8 * g;
#pragma unroll
    for (int e = 0; e < 8; e++) {
      const int j = 8 * g + e;
      bool c = d[j] < gv[g];
      gv[g] = c ? d[j] : gv[g];
      gj[g] = c ? j : gj[g];
    }
  }

  int* out = nbr + (size_t)cent * K;
  for (int r = 0; r < K; r++) {
    float bv = __builtin_inff();
    int bj = 0;
#pragma unroll
    for (int g = 0; g < 8; g++) {
      bool c = gv[g] < bv;
      bv = c ? gv[g] : bv;
      bj = c ? gj[g] : bj;
    }
    const unsigned bn = (unsigned)(bj * 64 + lane);
    const unsigned nb = ~__float_as_uint(bv);  // ~bits: umax -> min distance
    const unsigned wnb = wave_umax(nb);
    unsigned tk = (nb == wnb) ? (0xFFFFFFFFu - bn) : 0u;
    tk = wave_umax(tk);                        // ties -> smallest global n
    const unsigned wn = 0xFFFFFFFFu - tk;      // uniform across wave
    if (lane == 0) out[r] = (int)wn;

    const int wj = (int)(wn >> 6);
    const int wl = (int)(wn & 63);
    const int wg = wj >> 3;
#pragma unroll
    for (int g = 0; g < 8; g++) {
      if (g == wg) {
#pragma unroll
        for (int e = 0; e < 8; e++) {
          if (8 * g + e == wj) {
            if (lane == wl) d[8 * g + e] = __builtin_inff();
          }
        }
        float nv = __builtin_inff();
        int nj = 8 * g;
#pragma unroll
        for (int e = 0; e < 8; e++) {
          const int j = 8 * g + e;
          bool c = d[j] < nv;
          nv = c ? d[j] : nv;
          nj = c ? j : nj;
        }
        gv[g] = nv;
        gj[g] = nj;
      }
    }
  }
}

// ---------------------------------------------------------------------------
// Weight prep: W1t[n][k] = bf16(W1[k][n]) for k<67 else 0   (n<128, k<96)
//              W2t[n][k] = bf16(W2[k][n])                   (n<128, k<128)
// ---------------------------------------------------------------------------
__global__ __launch_bounds__(256) void prep_weights(const float* __restrict__ W1,
                                                    const float* __restrict__ W2,
                                                    unsigned short* __restrict__ W1t,
                                                    unsigned short* __restrict__ W2t) {
  const int n = blockIdx.x;    // 128
  const int t = threadIdx.x;   // 256
  if (t < K1) {
    W1t[n * K1 + t] = (t < 67) ? f2bf(W1[t * 128 + n]) : (unsigned short)0;
  } else if (t < K1 + 128) {
    int k = t - K1;
    W2t[n * 128 + k] = f2bf(W2[k * 128 + n]);
  }
}

// ---------------------------------------------------------------------------
// MLP v3: wave-per-centroid, ZERO barriers. 256 threads = 4 waves = 4 cents.
// A1 fragments built in registers; mish output crosses lanes via wave-private
// sA2 slice (within-wave RAW ordered by lgkmcnt).
// ---------------------------------------------------------------------------
__global__ __launch_bounds__(256) void mlp3_kernel(
    const float* __restrict__ x, const float* __restrict__ pos,
    const unsigned short* __restrict__ W1t, const unsigned short* __restrict__ W2t,
    const float* __restrict__ b1, const float* __restrict__ b2,
    const float* __restrict__ Wlin, const float* __restrict__ blin,
    const int* __restrict__ idx, const int* __restrict__ nbr,
    float* __restrict__ xout) {
  __shared__ unsigned short sA2[4][32][LDH];
  const int tid  = threadIdx.x;
  const int wv   = tid >> 6;
  const int lane = tid & 63;
  const int lrow = lane & 15;
  const int g    = lane >> 4;
  const int cent = blockIdx.x * 4 + wv;
  const int b    = cent >> 10;
  const int sel  = idx[cent];
  const float* pb = pos + (size_t)b * (N * 3);
  const float qx = pb[3 * sel + 0], qy = pb[3 * sel + 1], qz = pb[3 * sel + 2];
  unsigned short* A2 = &sA2[wv][0][0];

  const int n0 = nbr[(size_t)cent * K + lrow];
  const int n1 = nbr[(size_t)cent * K + 16 + lrow];

  // ---- build A1 fragments in registers ----
  short8 a0[3], a1[3];
  {
    const float* xr0 = x + ((size_t)b * N + n0) * CIN;
    const float* xr1 = x + ((size_t)b * N + n1) * CIN;
#pragma unroll
    for (int kc = 0; kc < 2; kc++) {
      const int k0 = kc * 32 + g * 8;
      f32x4 u0 = *(const f32x4*)(xr0 + k0);
      f32x4 u1 = *(const f32x4*)(xr0 + k0 + 4);
      f32x4 v0 = *(const f32x4*)(xr1 + k0);
      f32x4 v1 = *(const f32x4*)(xr1 + k0 + 4);
      short8 ha, hb;
#pragma unroll
      for (int e = 0; e < 4; e++) {
        ha[e] = (short)f2bf(u0[e]);
        ha[e + 4] = (short)f2bf(u1[e]);
        hb[e] = (short)f2bf(v0[e]);
        hb[e + 4] = (short)f2bf(v1[e]);
      }
      a0[kc] = ha;
      a1[kc] = hb;
    }
    short8 z = {};
    a0[2] = z;
    a1[2] = z;
    if (g == 0) {  // k = 64..71: {rel.x, rel.y, rel.z, 0...}
      float r0x = pb[3 * n0 + 0] - qx, r0y = pb[3 * n0 + 1] - qy, r0z = pb[3 * n0 + 2] - qz;
      float r1x = pb[3 * n1 + 0] - qx, r1y = pb[3 * n1 + 1] - qy, r1z = pb[3 * n1 + 2] - qz;
      a0[2][0] = (short)f2bf(r0x); a0[2][1] = (short)f2bf(r0y); a0[2][2] = (short)f2bf(r0z);
      a1[2][0] = (short)f2bf(r1x); a1[2][1] = (short)f2bf(r1y); a1[2][2] = (short)f2bf(r1z);
    }
  }

  // ---- layer 1: C1[32,128] = A1 @ W1t^T, mish -> sA2 (wave-private) ----
#pragma unroll 2
  for (int nt = 0; nt < 8; nt++) {
    const unsigned short* w1r = W1t + (size_t)(nt * 16 + lrow) * K1 + g * 8;
    f32x4 c0 = {}, c1 = {};
#pragma unroll
    for (int kc = 0; kc < 3; kc++) {
      short8 bfr = *(const short8*)(w1r + kc * 32);
      c0 = __builtin_amdgcn_mfma_f32_16x16x32_bf16(a0[kc], bfr, c0, 0, 0, 0);
      c1 = __builtin_amdgcn_mfma_f32_16x16x32_bf16(a1[kc], bfr, c1, 0, 0, 0);
    }
    const int colI = nt * 16 + lrow;
    const float bb = b1[colI];
#pragma unroll
    for (int reg = 0; reg < 4; reg++) {
      const int row = g * 4 + reg;  // C layout (m89): col=lane&15, row=(lane>>4)*4+reg
      A2[row * LDH + colI] = f2bf(fast_mish(c0[reg] + bb));
      A2[(16 + row) * LDH + colI] = f2bf(fast_mish(c1[reg] + bb));
    }
  }

  // xsel slice for this lane's k-range (k = g*16 .. g*16+15)
  f32x4 xq[4];
  {
    const float* xs = x + ((size_t)b * N + sel) * CIN + g * 16;
#pragma unroll
    for (int v = 0; v < 4; v++) xq[v] = *(const f32x4*)(xs + 4 * v);
  }

  // ---- layer 2 + max over 32 rows + epilogue ----
#pragma unroll 2
  for (int nt = 0; nt < 8; nt++) {
    const unsigned short* w2r = W2t + (size_t)(nt * 16 + lrow) * 128 + g * 8;
    f32x4 c0 = {}, c1 = {};
#pragma unroll
    for (int kc = 0; kc < 4; kc++) {
      short8 af0 = *(const short8*)(A2 + lrow * LDH + kc * 32 + g * 8);
      short8 af1 = *(const short8*)(A2 + (16 + lrow) * LDH + kc * 32 + g * 8);
      short8 bfr = *(const short8*)(w2r + kc * 32);
      c0 = __builtin_amdgcn_mfma_f32_16x16x32_bf16(af0, bfr, c0, 0, 0, 0);
      c1 = __builtin_amdgcn_mfma_f32_16x16x32_bf16(af1, bfr, c1, 0, 0, 0);
    }
    float pm = fmaxf(fmaxf(fmaxf(c0[0], c0[1]), fmaxf(c0[2], c0[3])),
                     fmaxf(fmaxf(c1[0], c1[1]), fmaxf(c1[2], c1[3])));
    pm = fmaxf(pm, __shfl_xor(pm, 16, 64));
    pm = fmaxf(pm, __shfl_xor(pm, 32, 64));  // max over all 32 rows, col j
    const int j = nt * 16 + lrow;
    float s = 0.f;
#pragma unroll
    for (int e = 0; e < 16; e++) {
      s += xq[e >> 2][e & 3] * Wlin[(g * 16 + e) * 128 + j];
    }
    s += __shfl_xor(s, 16, 64);
    s += __shfl_xor(s, 32, 64);  // full 64-k dot
    if (g == 0) {
      xout[(size_t)cent * 128 + j] = pm + b2[j] + s + blin[j];
    }
  }
}

// ---------------------------------------------------------------------------
extern "C" void kernel_launch(void* const* d_in, const int* in_sizes, int n_in,
                              void* d_out, int out_size, void* d_ws, size_t ws_size,
                              hipStream_t stream) {
  const float* x    = (const float*)d_in[0];
  const float* pos  = (const float*)d_in[1];
  const float* W1   = (const float*)d_in[2];
  const float* b1   = (const float*)d_in[3];
  const float* W2   = (const float*)d_in[4];
  const float* b2   = (const float*)d_in[5];
  const float* Wlin = (const float*)d_in[6];
  const float* blin = (const float*)d_in[7];

  float* out  = (float*)d_out;                 // float32 outputs
  float* xout = out;                           // [B*M*COUT]
  float* pout = out + (size_t)B * M * COUT;    // [B*M*3]

  char* ws = (char*)d_ws;
  int* idx            = (int*)ws;                                         // 64 KB
  int* nbr            = (int*)(ws + 65536);                               // 2 MB
  unsigned short* W1t = (unsigned short*)(ws + 65536 + 2097152);          // 24 KB
  unsigned short* W2t = (unsigned short*)(ws + 65536 + 2097152 + 24576);  // 32 KB
  float* pos4         = (float*)(ws + 65536 + 2097152 + 24576 + 32768);   // 1 MB

  prep_weights<<<dim3(128), dim3(256), 0, stream>>>(W1, W2, W1t, W2t);
  fps8_kernel<<<dim3(B), dim3(512), 0, stream>>>(pos, idx, pout, pos4);
  knn5_kernel<<<dim3(B * M / 4), dim3(256), 0, stream>>>(pos4, idx, nbr);
  mlp3_kernel<<<dim3(B * M / 4), dim3(256), 0, stream>>>(
      x, pos, W1t, W2t, b1, b2, Wlin, blin, idx, nbr, xout);
}